// Round 11
// baseline (1046.712 us; speedup 1.0000x reference)
//
#include <hip/hip_runtime.h>

typedef unsigned short u16;
typedef unsigned int   u32;

#define H    128
#define C    16
#define ODIM 128

typedef short bf16x8 __attribute__((ext_vector_type(8)));
typedef float f32x4  __attribute__((ext_vector_type(4)));
typedef float f32x2v __attribute__((ext_vector_type(2)));

#define WSP 272   // Ws row stride (u16)
#define NP  256   // CSR partitions

__device__ __forceinline__ float bf2f(u32 v){
  union { u32 i; float f; } t; t.i = v << 16; return t.f;
}
__device__ __forceinline__ u16 f2bf(float f){
  u32 u = __float_as_uint(f);
  u32 r = u + 0x7fffu + ((u >> 16) & 1u);   // RNE
  return (u16)(r >> 16);
}
__device__ __forceinline__ u32 pack2(float a, float b){
  return (u32)f2bf(a) | ((u32)f2bf(b) << 16);
}
__device__ __forceinline__ u32 pack_fp8x4(float a, float b, float c, float d){
  int p = __builtin_amdgcn_cvt_pk_fp8_f32(a, b, 0, false);
  p     = __builtin_amdgcn_cvt_pk_fp8_f32(c, d, p, true);
  return (u32)p;
}

// counters layout: [0]=scanA, [1..3]=linear per layer, [4..67]=clust per graph
#define NCTR 68

// ---------------- fused setup: embed | bounds(+ctr zero) | wprep | hist ------
__global__ __launch_bounds__(256) void k_setup(const float* __restrict__ emb,
    const int* __restrict__ deg, u16* __restrict__ xb, u32* __restrict__ xq,
    const int* __restrict__ batch, int* __restrict__ gs,
    const float* __restrict__ Wl, const float* __restrict__ Wr,
    u16* __restrict__ Wt, const int* __restrict__ ei,
    int* __restrict__ blkhist, int* __restrict__ counters,
    int N, int B, int NB, int E, int chunk, int g0, int g1, int g2){
  __shared__ __align__(16) char smem[4608];
  int bid = blockIdx.x, tid = threadIdx.x;
  if (bid < g0){
    // ---- embed ----
    int i = bid*256 + tid;
    if (i < N*32){
      int n = i >> 5, q = i & 31;
      int d = deg[n];
      float4 v = ((const float4*)(emb + (size_t)d*H))[q];
      uint2 o; o.x = pack2(v.x, v.y); o.y = pack2(v.z, v.w);
      ((uint2*)(xb + (size_t)n*H))[q] = o;
      xq[i] = pack_fp8x4(v.x, v.y, v.z, v.w);
    }
  } else if (bid < g1){
    // ---- bounds + counter zero ----
    if (bid == g0 && tid < NCTR) counters[tid] = 0;
    int n = (bid - g0)*256 + tid;
    if (n < N){
      int b = batch[n];
      if (n == 0){ for (int g = 0; g <= b; g++) gs[g] = 0; }
      else {
        int pb = batch[n-1];
        for (int g = pb+1; g <= b; g++) gs[g] = n;
      }
      if (n == N-1){ for (int g = b+1; g <= B; g++) gs[g] = N; }
    }
  } else if (bid < g2){
    // ---- wprep: Wt[l][h][k] ----
    u16 (*T)[18] = (u16(*)[18])smem;
    int b = bid - g1;
    int strip = b & 7, half = (b >> 3) & 1, l = b >> 4;
    const float* M = (half ? Wr : Wl) + (size_t)l*H*H;
    int k0 = strip * 16;
    #pragma unroll
    for (int j = 0; j < 8; j++){
      int u = tid + j*256;
      int kk = u >> 7, h = u & 127;
      T[h][kk] = f2bf(M[(size_t)(k0 + kk)*H + h]);
    }
    __syncthreads();
    #pragma unroll
    for (int j = 0; j < 8; j++){
      int u = tid + j*256;
      int h = u >> 4, k16 = u & 15;
      Wt[((size_t)(l*H + h))*256 + half*128 + k0 + k16] = T[h][k16];
    }
  } else {
    // ---- hist ----
    int* hist = (int*)smem;
    int blk = bid - g2;
    for (int b = tid; b < NB; b += 256) hist[b] = 0;
    __syncthreads();
    int start = blk*chunk, end = min(E, start + chunk);
    for (int e = start + tid; e < end; e += 256)
      atomicAdd(&hist[ei[E + e] >> 7], 1);
    __syncthreads();
    for (int b = tid; b < NB; b += 256) blkhist[b*NP + blk] = hist[b];
  }
}

// scan over n ints (1024/block); last block computes boff (fused scanB)
__global__ __launch_bounds__(256) void k_scanA(const int* __restrict__ in,
    int* __restrict__ out, int* __restrict__ bsum, int* __restrict__ boff,
    int* __restrict__ counters, int n){
  __shared__ int wsum[4];
  __shared__ int lastflag;
  int tid = threadIdx.x;
  int base = blockIdx.x*1024 + tid*4;
  int v0 = (base+0 < n) ? in[base+0] : 0;
  int v1 = (base+1 < n) ? in[base+1] : 0;
  int v2 = (base+2 < n) ? in[base+2] : 0;
  int v3 = (base+3 < n) ? in[base+3] : 0;
  int tsum = v0+v1+v2+v3;
  int lane = tid & 63, w = tid >> 6;
  int incl = tsum;
  for (int d = 1; d < 64; d <<= 1){
    int t = __shfl_up(incl, d, 64);
    if (lane >= d) incl += t;
  }
  if (lane == 63) wsum[w] = incl;
  __syncthreads();
  int woff = 0;
  for (int i = 0; i < w; i++) woff += wsum[i];
  int excl = woff + incl - tsum;
  if (base+0 < n) out[base+0] = excl;
  if (base+1 < n) out[base+1] = excl + v0;
  if (base+2 < n) out[base+2] = excl + v0 + v1;
  if (base+3 < n) out[base+3] = excl + v0 + v1 + v2;
  if (tid == 255) bsum[blockIdx.x] = woff + incl;
  __syncthreads();                       // drain stores (vmcnt) before fence
  if (tid == 0){
    __threadfence();
    lastflag = (atomicAdd(&counters[0], 1) == (int)gridDim.x - 1);
  }
  __syncthreads();
  if (lastflag){
    __threadfence();
    int nb = gridDim.x;
    int v = (tid < nb) ? bsum[tid] : 0;
    int incl2 = v;
    for (int d = 1; d < 64; d <<= 1){
      int t = __shfl_up(incl2, d, 64);
      if (lane >= d) incl2 += t;
    }
    if (lane == 63) wsum[w] = incl2;
    __syncthreads();
    int woff2 = 0;
    for (int i = 0; i < w; i++) woff2 += wsum[i];
    if (tid < nb) boff[tid] = woff2 + incl2 - v;
  }
}

// place edges bucket-sorted as (src,dst) pairs; boff folded into cursor init
__global__ __launch_bounds__(256) void k_place(const int* __restrict__ ei,
    const int* __restrict__ bases, const int* __restrict__ boff,
    int2* __restrict__ pairs, int NB, int E, int chunk){
  __shared__ int cursor[400];
  int blk = blockIdx.x, tid = threadIdx.x;
  for (int b = tid; b < NB; b += 256){
    int i = b*NP + blk;
    cursor[b] = bases[i] + boff[i >> 10];
  }
  __syncthreads();
  int start = blk*chunk, end = min(E, start + chunk);
  for (int e = start + tid; e < end; e += 256){
    int s = ei[e], d = ei[E + e];
    int pos = atomicAdd(&cursor[d >> 7], 1);
    pairs[pos] = make_int2(s, d);
  }
}

// per bucket: per-node counts -> rowptr (direct), then node-sort col
__global__ __launch_bounds__(256) void k_cnt_place(const int2* __restrict__ pairs,
    const int* __restrict__ bases, const int* __restrict__ boff,
    int* __restrict__ rowptr, int* __restrict__ col, int NB, int N, int E){
  int b = blockIdx.x, tid = threadIdx.x;
  int i0 = b*NP;
  int bstart = bases[i0] + boff[i0 >> 10];
  int bend = E;
  if (b+1 < NB){ int i1 = (b+1)*NP; bend = bases[i1] + boff[i1 >> 10]; }
  __shared__ int cnt[128], sc[128], rank[128];
  if (tid < 128) cnt[tid] = 0;
  __syncthreads();
  for (int e = bstart + tid; e < bend; e += 256)
    atomicAdd(&cnt[pairs[e].y & 127], 1);
  __syncthreads();
  if (tid < 128) sc[tid] = cnt[tid];
  for (int d = 1; d < 128; d <<= 1){
    int v = 0;
    __syncthreads();
    if (tid < 128 && tid >= d) v = sc[tid - d];
    __syncthreads();
    if (tid < 128) sc[tid] += v;
  }
  __syncthreads();
  if (tid < 128){
    int excl = sc[tid] - cnt[tid];
    rank[tid] = bstart + excl;
    int node = b*128 + tid;
    if (node < N) rowptr[node] = bstart + excl;
  }
  if (b == NB-1 && tid == 0) rowptr[N] = E;
  __syncthreads();
  for (int e = bstart + tid; e < bend; e += 256){
    int2 p = pairs[e];
    int pos = atomicAdd(&rank[p.y & 127], 1);
    col[pos] = p.x;
  }
}

// ---------------- per-layer ----------------
// wave per node; fp8 row = 128 B = 8 lanes x uint4, 8 edges/VMEM-instr,
// packed f32 accumulate (v_pk_add_f32).
__device__ __forceinline__ void dec16v(f32x2v* a, uint4 v){
  a[0] += __builtin_amdgcn_cvt_pk_f32_fp8((int)v.x, false);
  a[1] += __builtin_amdgcn_cvt_pk_f32_fp8((int)v.x, true );
  a[2] += __builtin_amdgcn_cvt_pk_f32_fp8((int)v.y, false);
  a[3] += __builtin_amdgcn_cvt_pk_f32_fp8((int)v.y, true );
  a[4] += __builtin_amdgcn_cvt_pk_f32_fp8((int)v.z, false);
  a[5] += __builtin_amdgcn_cvt_pk_f32_fp8((int)v.z, true );
  a[6] += __builtin_amdgcn_cvt_pk_f32_fp8((int)v.w, false);
  a[7] += __builtin_amdgcn_cvt_pk_f32_fp8((int)v.w, true );
}

__global__ __launch_bounds__(256) void k_agg(const u32* __restrict__ xq,
    const int* __restrict__ rowptr, const int* __restrict__ col,
    u16* __restrict__ meanb, int N){
  int wid  = (blockIdx.x*256 + threadIdx.x) >> 6;
  int lane = threadIdx.x & 63;
  if (wid >= N) return;
  int r0 = rowptr[wid], r1 = rowptr[wid+1];
  int grp = lane >> 3, fl = lane & 7;   // 8 groups x 8 lanes
  const u32* xf = xq + fl*4;            // 16 fp8 features per lane
  f32x2v a[8];
  #pragma unroll
  for (int j = 0; j < 8; j++) a[j] = (f32x2v){0.f, 0.f};
  int e = r0 + grp;
  for (; e + 8 < r1; e += 16){
    uint4 v = *(const uint4*)(xf + (size_t)col[e]*32);
    uint4 u = *(const uint4*)(xf + (size_t)col[e+8]*32);
    dec16v(a, v);
    dec16v(a, u);
  }
  if (e < r1){
    uint4 v = *(const uint4*)(xf + (size_t)col[e]*32);
    dec16v(a, v);
  }
  #pragma unroll
  for (int j = 0; j < 8; j++){
    a[j].x += __shfl_xor(a[j].x, 8, 64);  a[j].y += __shfl_xor(a[j].y, 8, 64);
    a[j].x += __shfl_xor(a[j].x, 16, 64); a[j].y += __shfl_xor(a[j].y, 16, 64);
    a[j].x += __shfl_xor(a[j].x, 32, 64); a[j].y += __shfl_xor(a[j].y, 32, 64);
  }
  if (grp == 0){
    float invc = 1.0f / (float)max(r1 - r0, 1);
    uint4 o0, o1;
    o0.x = pack2(a[0].x*invc, a[0].y*invc);
    o0.y = pack2(a[1].x*invc, a[1].y*invc);
    o0.z = pack2(a[2].x*invc, a[2].y*invc);
    o0.w = pack2(a[3].x*invc, a[3].y*invc);
    o1.x = pack2(a[4].x*invc, a[4].y*invc);
    o1.y = pack2(a[5].x*invc, a[5].y*invc);
    o1.z = pack2(a[6].x*invc, a[6].y*invc);
    o1.w = pack2(a[7].x*invc, a[7].y*invc);
    u16* mp = meanb + (size_t)wid*H + fl*16;
    *(uint4*)mp       = o0;
    *(uint4*)(mp + 8) = o1;
  }
}

// x2b[n][h] (bf16) = bl[h] + [meanb|xb] @ Wt^T via mfma_f32_16x16x32_bf16.
// Wt staged whole in LDS; A-fragments direct from global. BN-stat partials
// -> pstats; LAST block reduces pstats -> stats (fused statred).
__global__ __launch_bounds__(256) void k_linear(const u16* __restrict__ meanb,
    const u16* __restrict__ xb, const u16* __restrict__ Wt,
    const float* __restrict__ bl, u16* __restrict__ x2b,
    float* __restrict__ pstats, float* __restrict__ stats,
    int* __restrict__ counters, int l, int N){
  __shared__ u16 Ws[128][WSP];         // 69.6 KB
  __shared__ float Sh[128], Qh[128];
  __shared__ int lastflag;
  int tid = threadIdx.x;
  if (tid < 128){ Sh[tid] = 0.f; Qh[tid] = 0.f; }
  int lane = tid & 63, w = tid >> 6;
  int mlane = lane & 15, quad = lane >> 4;
  int node = blockIdx.x*64 + w*16 + mlane;
  const u16* arow_m = meanb + (size_t)node*H + quad*8;
  const u16* arow_x = xb   + (size_t)node*H + quad*8;
  bf16x8 af[8];
  #pragma unroll
  for (int kk = 0; kk < 4; kk++){
    af[kk]     = *(const bf16x8*)(arow_m + kk*32);
    af[kk + 4] = *(const bf16x8*)(arow_x + kk*32);
  }
  #pragma unroll
  for (int j = 0; j < 16; j++){
    int u = tid + j*256;
    int row = u >> 5, seg = u & 31;
    uint4 v = ((const uint4*)(Wt + (size_t)row*256))[seg];
    *(uint4*)&Ws[row][seg*8] = v;
  }
  __syncthreads();
  f32x4 acc[8];
  #pragma unroll
  for (int t = 0; t < 8; t++) acc[t] = (f32x4){0.f, 0.f, 0.f, 0.f};
  #pragma unroll
  for (int kk = 0; kk < 8; kk++){
    #pragma unroll
    for (int t = 0; t < 8; t++){
      bf16x8 b = *(const bf16x8*)&Ws[t*16 + mlane][kk*32 + quad*8];
      acc[t] = __builtin_amdgcn_mfma_f32_16x16x32_bf16(af[kk], b, acc[t], 0, 0, 0);
    }
  }
  #pragma unroll
  for (int t = 0; t < 8; t++){
    int h = t*16 + mlane;
    float bv = bl[h];
    float s = 0.f, q = 0.f;
    #pragma unroll
    for (int r = 0; r < 4; r++){
      int nd = blockIdx.x*64 + w*16 + quad*4 + r;
      if (nd < N){
        float v = acc[t][r] + bv;
        x2b[(size_t)nd*H + h] = f2bf(v);
        s += v; q = fmaf(v, v, q);
      }
    }
    s += __shfl_xor(s, 16, 64); s += __shfl_xor(s, 32, 64);
    q += __shfl_xor(q, 16, 64); q += __shfl_xor(q, 32, 64);
    if (quad == 0){
      atomicAdd(&Sh[h], s);
      atomicAdd(&Qh[h], q);
    }
  }
  __syncthreads();
  {
    float v = (tid < 128) ? Sh[tid] : Qh[tid - 128];
    pstats[(size_t)blockIdx.x*256 + tid] = v;
  }
  __syncthreads();                       // drain pstats store before fence
  if (tid == 0){
    __threadfence();
    lastflag = (atomicAdd(&counters[1 + l], 1) == (int)gridDim.x - 1);
  }
  __syncthreads();
  if (lastflag){
    __threadfence();
    int nblk = gridDim.x;
    float s = 0.f;
    for (int b = 0; b < nblk; b++)
      s += pstats[(size_t)b*256 + tid];
    stats[tid] = s;
  }
}

// BN+ReLU (reads bf16 x2b); writes xb + xq; do_scores fuses attention scores.
__global__ __launch_bounds__(256) void k_bnrelu(const u16* __restrict__ x2b,
    const float* __restrict__ stats, const float* __restrict__ gamma,
    const float* __restrict__ beta, u16* __restrict__ xb, u32* __restrict__ xq,
    int N, float invN,
    const float* __restrict__ attn_W, const float* __restrict__ attn_b,
    float* __restrict__ escore, int do_scores){
  __shared__ float xs[8][132];
  __shared__ float aw[H*C];
  __shared__ float ab[C];
  int tid = threadIdx.x;
  int i = blockIdx.x*256 + tid;
  bool active = (i < N*32);
  int h = (tid & 31) * 4;
  float r[4] = {0.f, 0.f, 0.f, 0.f};
  if (active){
    uint2 o2 = ((const uint2*)x2b)[i];
    float vv[4] = {bf2f(o2.x & 0xffff), bf2f(o2.x >> 16),
                   bf2f(o2.y & 0xffff), bf2f(o2.y >> 16)};
    #pragma unroll
    for (int j = 0; j < 4; j++){
      float mu  = stats[h+j] * invN;
      float var = fmaf(-mu, mu, stats[H + h + j] * invN);
      float sc  = rsqrtf(var + 1e-5f) * gamma[h+j];
      float bi  = beta[h+j];
      r[j] = fmaxf(fmaf(vv[j] - mu, sc, bi), 0.0f);
    }
    uint2 o; o.x = pack2(r[0], r[1]); o.y = pack2(r[2], r[3]);
    ((uint2*)xb)[i] = o;
    xq[i] = pack_fp8x4(r[0], r[1], r[2], r[3]);
  }
  if (do_scores){
    #pragma unroll
    for (int j = 0; j < 8; j++) aw[tid + j*256] = attn_W[tid + j*256];
    if (tid < C) ab[tid] = attn_b[tid];
    int ln = tid >> 5;
    if (active){
      xs[ln][h+0]=r[0]; xs[ln][h+1]=r[1]; xs[ln][h+2]=r[2]; xs[ln][h+3]=r[3];
    }
    __syncthreads();
    if (tid < 128){
      int n2 = tid >> 4, c = tid & 15;
      int node = blockIdx.x*8 + n2;
      if (node < N){
        float acc = ab[c];
        #pragma unroll 4
        for (int k = 0; k < H; k++)
          acc = fmaf(xs[n2][k], aw[k*C + c], acc);
        escore[(size_t)node*C + c] = __expf(acc);
      }
    }
  }
}

// partial[g][b][c][h]; LAST of graph g's 16 blocks computes denom + output
// rows for graph g (fused k_out).
__global__ __launch_bounds__(256) void k_clust(const u16* __restrict__ xb,
    const float* __restrict__ escore, const int* __restrict__ gs,
    float* __restrict__ partial, int* __restrict__ counters,
    const float* __restrict__ out_W, const float* __restrict__ out_b,
    float* __restrict__ out){
  __shared__ float cs[16][129];
  __shared__ float dpart[16][17];
  __shared__ float dinv[16];
  __shared__ int lastflag;
  int g = blockIdx.x >> 4, b = blockIdx.x & 15;
  int tid = threadIdx.x;
  int h = tid & 127, cg = tid >> 7;
  int a = gs[g], e2 = gs[g+1];
  float acc[8] = {0,0,0,0,0,0,0,0};
  for (int n = a + b; n < e2; n += 16){
    float xv = bf2f(xb[(size_t)n*H + h]);
    const float4* ep = (const float4*)(escore + (size_t)n*C) + cg*2;
    float4 e0 = ep[0], e1 = ep[1];
    acc[0] = fmaf(e0.x, xv, acc[0]);
    acc[1] = fmaf(e0.y, xv, acc[1]);
    acc[2] = fmaf(e0.z, xv, acc[2]);
    acc[3] = fmaf(e0.w, xv, acc[3]);
    acc[4] = fmaf(e1.x, xv, acc[4]);
    acc[5] = fmaf(e1.y, xv, acc[5]);
    acc[6] = fmaf(e1.z, xv, acc[6]);
    acc[7] = fmaf(e1.w, xv, acc[7]);
  }
  int c0 = cg*8;
  float* dst = partial + (((size_t)(g*16 + b))*C)*H + h;
  #pragma unroll
  for (int r = 0; r < 8; r++)
    dst[(size_t)(c0 + r)*H] = acc[r];
  __syncthreads();                       // drain partial stores
  if (tid == 0){
    __threadfence();
    lastflag = (atomicAdd(&counters[4 + g], 1) == 15);
  }
  __syncthreads();
  if (!lastflag) return;
  __threadfence();
  // cluster sums cs[c][h]
  for (int u = tid; u < C*H; u += 256){
    int c = u >> 7, hh = u & 127;
    float s = 0.f;
    #pragma unroll 4
    for (int b2 = 0; b2 < 16; b2++)
      s += partial[(((size_t)(g*16 + b2))*C + c)*H + hh];
    cs[c][hh] = s;
  }
  // denom
  {
    int c = tid & 15, sub = tid >> 4;
    float s = 0.f;
    for (int n = a + sub; n < e2; n += 16) s += escore[(size_t)n*C + c];
    dpart[sub][c] = s;
    __syncthreads();
    if (tid < 16){
      float t2 = 0.f;
      #pragma unroll
      for (int sb = 0; sb < 16; sb++) t2 += dpart[sb][tid];
      dinv[tid] = t2 > 0.f ? 1.0f/t2 : 0.f;
    }
  }
  __syncthreads();
  // output rows for this graph: 16 c x 128 o
  for (int u = tid; u < C*ODIM; u += 256){
    int c = u >> 7, o = u & 127;
    float acc2 = 0.f;
    #pragma unroll 4
    for (int hh = 0; hh < H; hh++)
      acc2 = fmaf(cs[c][hh], out_W[hh*ODIM + o], acc2);
    out[((size_t)(g*16 + c))*ODIM + o] = fmaf(acc2, dinv[c], out_b[o]);
  }
}

// ---------------- host ----------------
extern "C" void kernel_launch(void* const* d_in, const int* in_sizes, int n_in,
                              void* d_out, int out_size, void* d_ws, size_t ws_size,
                              hipStream_t stream){
  const float* emb    = (const float*)d_in[0];
  const float* Wl     = (const float*)d_in[1];
  const float* bl     = (const float*)d_in[2];
  const float* Wr     = (const float*)d_in[3];
  const float* gamma  = (const float*)d_in[4];
  const float* beta   = (const float*)d_in[5];
  const float* attn_W = (const float*)d_in[6];
  const float* attn_b = (const float*)d_in[7];
  const float* out_W  = (const float*)d_in[8];
  const float* out_b  = (const float*)d_in[9];
  const int* deg    = (const int*)d_in[10];
  const int* ei     = (const int*)d_in[11];
  const int* batch  = (const int*)d_in[12];
  float* out = (float*)d_out;

  const int N = in_sizes[10];
  const int E = in_sizes[11] / 2;
  const int L = in_sizes[1] / (H*H);
  const int B = out_size / (C*ODIM);
  const int NB = (N + 127) >> 7;        // buckets of 128 nodes
  const int nbh = NB * NP;              // blkhist elements
  const int chunk = (E + NP - 1) / NP;  // edges per hist/place block
  const int nblkL = (N + 63) / 64;      // k_linear grid

  size_t off = 0;
  auto alloc = [&](size_t bytes) -> void* {
    void* p = (char*)d_ws + off;
    off += (bytes + 255) & ~(size_t)255;
    return p;
  };
  u16*   xb     = (u16*)  alloc((size_t)N*H*2);
  u32*   xq     = (u32*)  alloc((size_t)N*H);    // fp8 shadow of xb
  u16*   meanb  = (u16*)  alloc((size_t)N*H*2);
  u16*   x2b    = (u16*)  alloc((size_t)N*H*2);  // aliased: pairs, partial
  int2*  pairs  = (int2*)x2b;
  float* partial= (float*)x2b;
  u16*   Wt     = (u16*)  alloc((size_t)L*H*256*2);
  float* escore = (float*)alloc((size_t)N*C*4);
  int*   col    = (int*)  alloc((size_t)E*4);
  int*   rowptr = (int*)  alloc((size_t)(N+1)*4);
  int*   blkhist= (int*)  alloc((size_t)nbh*4);
  int*   bases  = (int*)  alloc((size_t)nbh*4);
  int*   bsum   = (int*)  alloc(256*4);
  int*   boff   = (int*)  alloc(256*4);
  int*   gs     = (int*)  alloc((size_t)(B+1)*4);
  float* stats  = (float*)alloc((size_t)L*2*H*4);
  float* pstats = (float*)alloc((size_t)nblkL*256*4);
  int*   counters=(int*)  alloc(NCTR*4);

  // fused setup
  int g0 = (N*32 + 255)/256;            // embed blocks
  int g1 = g0 + (N + 255)/256;          // + bounds
  int g2 = g1 + L*16;                   // + wprep
  int gT = g2 + NP;                     // + hist
  hipLaunchKernelGGL(k_setup, dim3(gT), dim3(256), 0, stream,
                     emb, deg, xb, xq, batch, gs, Wl, Wr, Wt, ei, blkhist,
                     counters, N, B, NB, E, chunk, g0, g1, g2);
  int nblkS = (nbh + 1023) / 1024;
  hipLaunchKernelGGL(k_scanA, dim3(nblkS), dim3(256), 0, stream,
                     blkhist, bases, bsum, boff, counters, nbh);
  hipLaunchKernelGGL(k_place, dim3(NP), dim3(256), 0, stream,
                     ei, bases, boff, pairs, NB, E, chunk);
  hipLaunchKernelGGL(k_cnt_place, dim3(NB), dim3(256), 0, stream,
                     pairs, bases, boff, rowptr, col, NB, N, E);

  float invN = 1.0f / (float)N;
  for (int l = 0; l < L; l++){
    hipLaunchKernelGGL(k_agg,    dim3((N+3)/4),  dim3(256), 0, stream, xq, rowptr, col, meanb, N);
    hipLaunchKernelGGL(k_linear, dim3(nblkL),    dim3(256), 0, stream,
                       meanb, xb, Wt + (size_t)l*H*256, bl + (size_t)l*H, x2b,
                       pstats, stats + l*2*H, counters, l, N);
    hipLaunchKernelGGL(k_bnrelu, dim3((N*32+255)/256), dim3(256), 0, stream,
                       x2b, stats + l*2*H, gamma + (size_t)l*H, beta + (size_t)l*H,
                       xb, xq, N, invN, attn_W, attn_b, escore, (l == L-1) ? 1 : 0);
  }
  hipLaunchKernelGGL(k_clust, dim3(B*16), dim3(256), 0, stream,
                     xb, escore, gs, partial, counters, out_W, out_b, out);
}

// Round 13
// 335.518 us; speedup vs baseline: 3.1197x; 3.1197x over previous
//
#include <hip/hip_runtime.h>

typedef unsigned short u16;
typedef unsigned int   u32;

#define H    128
#define C    16
#define ODIM 128

typedef short bf16x8 __attribute__((ext_vector_type(8)));
typedef float f32x4  __attribute__((ext_vector_type(4)));
typedef float f32x2v __attribute__((ext_vector_type(2)));

#define WSP 272   // Ws row stride (u16)
#define NP  256   // CSR partitions

__device__ __forceinline__ float bf2f(u32 v){
  union { u32 i; float f; } t; t.i = v << 16; return t.f;
}
__device__ __forceinline__ u16 f2bf(float f){
  u32 u = __float_as_uint(f);
  u32 r = u + 0x7fffu + ((u >> 16) & 1u);   // RNE
  return (u16)(r >> 16);
}
__device__ __forceinline__ u32 pack2(float a, float b){
  return (u32)f2bf(a) | ((u32)f2bf(b) << 16);
}
__device__ __forceinline__ u32 pack_fp8x4(float a, float b, float c, float d){
  int p = __builtin_amdgcn_cvt_pk_fp8_f32(a, b, 0, false);
  p     = __builtin_amdgcn_cvt_pk_fp8_f32(c, d, p, true);
  return (u32)p;
}

// ---------------- fused setup: embed | bounds | wprep | hist ----------------
__global__ __launch_bounds__(256) void k_setup(const float* __restrict__ emb,
    const int* __restrict__ deg, u16* __restrict__ xb, u32* __restrict__ xq,
    const int* __restrict__ batch, int* __restrict__ gs,
    const float* __restrict__ Wl, const float* __restrict__ Wr,
    u16* __restrict__ Wt, const int* __restrict__ ei,
    int* __restrict__ blkhist, int N, int B, int NB, int E, int chunk,
    int g0, int g1, int g2){
  __shared__ __align__(16) char smem[4608];
  int bid = blockIdx.x, tid = threadIdx.x;
  if (bid < g0){
    // ---- embed ----
    int i = bid*256 + tid;
    if (i < N*32){
      int n = i >> 5, q = i & 31;
      int d = deg[n];
      float4 v = ((const float4*)(emb + (size_t)d*H))[q];
      uint2 o; o.x = pack2(v.x, v.y); o.y = pack2(v.z, v.w);
      ((uint2*)(xb + (size_t)n*H))[q] = o;
      xq[i] = pack_fp8x4(v.x, v.y, v.z, v.w);
    }
  } else if (bid < g1){
    // ---- bounds ----
    int n = (bid - g0)*256 + tid;
    if (n < N){
      int b = batch[n];
      if (n == 0){ for (int g = 0; g <= b; g++) gs[g] = 0; }
      else {
        int pb = batch[n-1];
        for (int g = pb+1; g <= b; g++) gs[g] = n;
      }
      if (n == N-1){ for (int g = b+1; g <= B; g++) gs[g] = N; }
    }
  } else if (bid < g2){
    // ---- wprep: Wt[l][h][k] ----
    u16 (*T)[18] = (u16(*)[18])smem;
    int b = bid - g1;
    int strip = b & 7, half = (b >> 3) & 1, l = b >> 4;
    const float* M = (half ? Wr : Wl) + (size_t)l*H*H;
    int k0 = strip * 16;
    #pragma unroll
    for (int j = 0; j < 8; j++){
      int u = tid + j*256;
      int kk = u >> 7, h = u & 127;
      T[h][kk] = f2bf(M[(size_t)(k0 + kk)*H + h]);
    }
    __syncthreads();
    #pragma unroll
    for (int j = 0; j < 8; j++){
      int u = tid + j*256;
      int h = u >> 4, k16 = u & 15;
      Wt[((size_t)(l*H + h))*256 + half*128 + k0 + k16] = T[h][k16];
    }
  } else {
    // ---- hist ----
    int* hist = (int*)smem;
    int blk = bid - g2;
    for (int b = tid; b < NB; b += 256) hist[b] = 0;
    __syncthreads();
    int start = blk*chunk, end = min(E, start + chunk);
    for (int e = start + tid; e < end; e += 256)
      atomicAdd(&hist[ei[E + e] >> 7], 1);
    __syncthreads();
    for (int b = tid; b < NB; b += 256) blkhist[b*NP + blk] = hist[b];
  }
}

// generic scan over n ints (1024 per block)
__global__ __launch_bounds__(256) void k_scanA(const int* __restrict__ in,
    int* __restrict__ out, int* __restrict__ bsum, int n){
  __shared__ int wsum[4];
  int tid = threadIdx.x;
  int base = blockIdx.x*1024 + tid*4;
  int v0 = (base+0 < n) ? in[base+0] : 0;
  int v1 = (base+1 < n) ? in[base+1] : 0;
  int v2 = (base+2 < n) ? in[base+2] : 0;
  int v3 = (base+3 < n) ? in[base+3] : 0;
  int tsum = v0+v1+v2+v3;
  int lane = tid & 63, w = tid >> 6;
  int incl = tsum;
  for (int d = 1; d < 64; d <<= 1){
    int t = __shfl_up(incl, d, 64);
    if (lane >= d) incl += t;
  }
  if (lane == 63) wsum[w] = incl;
  __syncthreads();
  int woff = 0;
  for (int i = 0; i < w; i++) woff += wsum[i];
  int excl = woff + incl - tsum;
  if (base+0 < n) out[base+0] = excl;
  if (base+1 < n) out[base+1] = excl + v0;
  if (base+2 < n) out[base+2] = excl + v0 + v1;
  if (base+3 < n) out[base+3] = excl + v0 + v1 + v2;
  if (tid == 255) bsum[blockIdx.x] = woff + incl;
}

// scan of up to 256 block sums
__global__ __launch_bounds__(256) void k_scanB(const int* __restrict__ bsum,
    int* __restrict__ boff, int nb){
  __shared__ int ws[4];
  int tid = threadIdx.x;
  int v = (tid < nb) ? bsum[tid] : 0;
  int lane = tid & 63, w = tid >> 6;
  int incl = v;
  for (int d = 1; d < 64; d <<= 1){
    int t = __shfl_up(incl, d, 64);
    if (lane >= d) incl += t;
  }
  if (lane == 63) ws[w] = incl;
  __syncthreads();
  int woff = 0;
  for (int i = 0; i < w; i++) woff += ws[i];
  boff[tid] = woff + incl - v;
}

// place edges bucket-sorted as (src,dst) pairs; boff folded into cursor init
__global__ __launch_bounds__(256) void k_place(const int* __restrict__ ei,
    const int* __restrict__ bases, const int* __restrict__ boff,
    int2* __restrict__ pairs, int NB, int E, int chunk){
  __shared__ int cursor[400];
  int blk = blockIdx.x, tid = threadIdx.x;
  for (int b = tid; b < NB; b += 256){
    int i = b*NP + blk;
    cursor[b] = bases[i] + boff[i >> 10];
  }
  __syncthreads();
  int start = blk*chunk, end = min(E, start + chunk);
  for (int e = start + tid; e < end; e += 256){
    int s = ei[e], d = ei[E + e];
    int pos = atomicAdd(&cursor[d >> 7], 1);
    pairs[pos] = make_int2(s, d);
  }
}

// per bucket: per-node counts -> rowptr (direct), then node-sort col
__global__ __launch_bounds__(256) void k_cnt_place(const int2* __restrict__ pairs,
    const int* __restrict__ bases, const int* __restrict__ boff,
    int* __restrict__ rowptr, int* __restrict__ col, int NB, int N, int E){
  int b = blockIdx.x, tid = threadIdx.x;
  int i0 = b*NP;
  int bstart = bases[i0] + boff[i0 >> 10];
  int bend = E;
  if (b+1 < NB){ int i1 = (b+1)*NP; bend = bases[i1] + boff[i1 >> 10]; }
  __shared__ int cnt[128], sc[128], rank[128];
  if (tid < 128) cnt[tid] = 0;
  __syncthreads();
  for (int e = bstart + tid; e < bend; e += 256)
    atomicAdd(&cnt[pairs[e].y & 127], 1);
  __syncthreads();
  if (tid < 128) sc[tid] = cnt[tid];
  for (int d = 1; d < 128; d <<= 1){
    int v = 0;
    __syncthreads();
    if (tid < 128 && tid >= d) v = sc[tid - d];
    __syncthreads();
    if (tid < 128) sc[tid] += v;
  }
  __syncthreads();
  if (tid < 128){
    int excl = sc[tid] - cnt[tid];
    rank[tid] = bstart + excl;
    int node = b*128 + tid;
    if (node < N) rowptr[node] = bstart + excl;
  }
  if (b == NB-1 && tid == 0) rowptr[N] = E;
  __syncthreads();
  for (int e = bstart + tid; e < bend; e += 256){
    int2 p = pairs[e];
    int pos = atomicAdd(&rank[p.y & 127], 1);
    col[pos] = p.x;
  }
}

// ---------------- per-layer ----------------
// wave per node; fp8 row = 128 B = 8 lanes x uint4, 8 edges/VMEM-instr,
// packed f32 accumulate (v_pk_add_f32).
__device__ __forceinline__ void dec16v(f32x2v* a, uint4 v){
  a[0] += __builtin_amdgcn_cvt_pk_f32_fp8((int)v.x, false);
  a[1] += __builtin_amdgcn_cvt_pk_f32_fp8((int)v.x, true );
  a[2] += __builtin_amdgcn_cvt_pk_f32_fp8((int)v.y, false);
  a[3] += __builtin_amdgcn_cvt_pk_f32_fp8((int)v.y, true );
  a[4] += __builtin_amdgcn_cvt_pk_f32_fp8((int)v.z, false);
  a[5] += __builtin_amdgcn_cvt_pk_f32_fp8((int)v.z, true );
  a[6] += __builtin_amdgcn_cvt_pk_f32_fp8((int)v.w, false);
  a[7] += __builtin_amdgcn_cvt_pk_f32_fp8((int)v.w, true );
}

__global__ __launch_bounds__(256) void k_agg(const u32* __restrict__ xq,
    const int* __restrict__ rowptr, const int* __restrict__ col,
    u16* __restrict__ meanb, int N){
  int wid  = (blockIdx.x*256 + threadIdx.x) >> 6;
  int lane = threadIdx.x & 63;
  if (wid >= N) return;
  int r0 = rowptr[wid], r1 = rowptr[wid+1];
  int grp = lane >> 3, fl = lane & 7;   // 8 groups x 8 lanes
  const u32* xf = xq + fl*4;            // 16 fp8 features per lane
  f32x2v a[8];
  #pragma unroll
  for (int j = 0; j < 8; j++) a[j] = (f32x2v){0.f, 0.f};
  int e = r0 + grp;
  for (; e + 8 < r1; e += 16){
    uint4 v = *(const uint4*)(xf + (size_t)col[e]*32);
    uint4 u = *(const uint4*)(xf + (size_t)col[e+8]*32);
    dec16v(a, v);
    dec16v(a, u);
  }
  if (e < r1){
    uint4 v = *(const uint4*)(xf + (size_t)col[e]*32);
    dec16v(a, v);
  }
  #pragma unroll
  for (int j = 0; j < 8; j++){
    a[j].x += __shfl_xor(a[j].x, 8, 64);  a[j].y += __shfl_xor(a[j].y, 8, 64);
    a[j].x += __shfl_xor(a[j].x, 16, 64); a[j].y += __shfl_xor(a[j].y, 16, 64);
    a[j].x += __shfl_xor(a[j].x, 32, 64); a[j].y += __shfl_xor(a[j].y, 32, 64);
  }
  if (grp == 0){
    float invc = 1.0f / (float)max(r1 - r0, 1);
    uint4 o0, o1;
    o0.x = pack2(a[0].x*invc, a[0].y*invc);
    o0.y = pack2(a[1].x*invc, a[1].y*invc);
    o0.z = pack2(a[2].x*invc, a[2].y*invc);
    o0.w = pack2(a[3].x*invc, a[3].y*invc);
    o1.x = pack2(a[4].x*invc, a[4].y*invc);
    o1.y = pack2(a[5].x*invc, a[5].y*invc);
    o1.z = pack2(a[6].x*invc, a[6].y*invc);
    o1.w = pack2(a[7].x*invc, a[7].y*invc);
    u16* mp = meanb + (size_t)wid*H + fl*16;
    *(uint4*)mp       = o0;
    *(uint4*)(mp + 8) = o1;
  }
}

// x2b[n][h] (bf16) = bl[h] + [meanb|xb] @ Wt^T via mfma_f32_16x16x32_bf16.
// Wt staged whole in LDS; A-fragments direct from global. Fused BN-stat
// partials -> pstats[blk][256]. (No fences — statred is a separate kernel.)
__global__ __launch_bounds__(256) void k_linear(const u16* __restrict__ meanb,
    const u16* __restrict__ xb, const u16* __restrict__ Wt,
    const float* __restrict__ bl, u16* __restrict__ x2b,
    float* __restrict__ pstats, int N){
  __shared__ u16 Ws[128][WSP];         // 69.6 KB -> 2 blocks/CU
  __shared__ float Sh[128], Qh[128];
  int tid = threadIdx.x;
  if (tid < 128){ Sh[tid] = 0.f; Qh[tid] = 0.f; }
  int lane = tid & 63, w = tid >> 6;
  int mlane = lane & 15, quad = lane >> 4;
  int node = blockIdx.x*64 + w*16 + mlane;
  const u16* arow_m = meanb + (size_t)node*H + quad*8;
  const u16* arow_x = xb   + (size_t)node*H + quad*8;
  bf16x8 af[8];
  #pragma unroll
  for (int kk = 0; kk < 4; kk++){
    af[kk]     = *(const bf16x8*)(arow_m + kk*32);
    af[kk + 4] = *(const bf16x8*)(arow_x + kk*32);
  }
  #pragma unroll
  for (int j = 0; j < 16; j++){
    int u = tid + j*256;
    int row = u >> 5, seg = u & 31;
    uint4 v = ((const uint4*)(Wt + (size_t)row*256))[seg];
    *(uint4*)&Ws[row][seg*8] = v;
  }
  __syncthreads();
  f32x4 acc[8];
  #pragma unroll
  for (int t = 0; t < 8; t++) acc[t] = (f32x4){0.f, 0.f, 0.f, 0.f};
  #pragma unroll
  for (int kk = 0; kk < 8; kk++){
    #pragma unroll
    for (int t = 0; t < 8; t++){
      bf16x8 b = *(const bf16x8*)&Ws[t*16 + mlane][kk*32 + quad*8];
      acc[t] = __builtin_amdgcn_mfma_f32_16x16x32_bf16(af[kk], b, acc[t], 0, 0, 0);
    }
  }
  #pragma unroll
  for (int t = 0; t < 8; t++){
    int h = t*16 + mlane;
    float bv = bl[h];
    float s = 0.f, q = 0.f;
    #pragma unroll
    for (int r = 0; r < 4; r++){
      int nd = blockIdx.x*64 + w*16 + quad*4 + r;
      if (nd < N){
        float v = acc[t][r] + bv;
        x2b[(size_t)nd*H + h] = f2bf(v);
        s += v; q = fmaf(v, v, q);
      }
    }
    s += __shfl_xor(s, 16, 64); s += __shfl_xor(s, 32, 64);
    q += __shfl_xor(q, 16, 64); q += __shfl_xor(q, 32, 64);
    if (quad == 0){
      atomicAdd(&Sh[h], s);
      atomicAdd(&Qh[h], q);
    }
  }
  __syncthreads();
  {
    float v = (tid < 128) ? Sh[tid] : Qh[tid - 128];
    pstats[(size_t)blockIdx.x*256 + tid] = v;
  }
}

// reduce pstats[nblk][256] -> stats[256]
__global__ __launch_bounds__(256) void k_statred(const float* __restrict__ pstats,
    float* __restrict__ stats, int nblk){
  __shared__ float red[4];
  int c = blockIdx.x, tid = threadIdx.x;
  float s = 0.f;
  for (int b = tid; b < nblk; b += 256)
    s += pstats[(size_t)b*256 + c];
  s += __shfl_xor(s, 1, 64);  s += __shfl_xor(s, 2, 64);
  s += __shfl_xor(s, 4, 64);  s += __shfl_xor(s, 8, 64);
  s += __shfl_xor(s, 16, 64); s += __shfl_xor(s, 32, 64);
  if ((tid & 63) == 0) red[tid >> 6] = s;
  __syncthreads();
  if (tid == 0) stats[c] = red[0] + red[1] + red[2] + red[3];
}

// BN+ReLU (reads bf16 x2b); writes xb + xq; do_scores fuses attention scores.
__global__ __launch_bounds__(256) void k_bnrelu(const u16* __restrict__ x2b,
    const float* __restrict__ stats, const float* __restrict__ gamma,
    const float* __restrict__ beta, u16* __restrict__ xb, u32* __restrict__ xq,
    int N, float invN,
    const float* __restrict__ attn_W, const float* __restrict__ attn_b,
    float* __restrict__ escore, int do_scores){
  __shared__ float xs[8][132];
  __shared__ float aw[H*C];
  __shared__ float ab[C];
  int tid = threadIdx.x;
  int i = blockIdx.x*256 + tid;
  bool active = (i < N*32);
  int h = (tid & 31) * 4;
  float r[4] = {0.f, 0.f, 0.f, 0.f};
  if (active){
    uint2 o2 = ((const uint2*)x2b)[i];
    float vv[4] = {bf2f(o2.x & 0xffff), bf2f(o2.x >> 16),
                   bf2f(o2.y & 0xffff), bf2f(o2.y >> 16)};
    #pragma unroll
    for (int j = 0; j < 4; j++){
      float mu  = stats[h+j] * invN;
      float var = fmaf(-mu, mu, stats[H + h + j] * invN);
      float sc  = rsqrtf(var + 1e-5f) * gamma[h+j];
      float bi  = beta[h+j];
      r[j] = fmaxf(fmaf(vv[j] - mu, sc, bi), 0.0f);
    }
    uint2 o; o.x = pack2(r[0], r[1]); o.y = pack2(r[2], r[3]);
    ((uint2*)xb)[i] = o;
    xq[i] = pack_fp8x4(r[0], r[1], r[2], r[3]);
  }
  if (do_scores){
    #pragma unroll
    for (int j = 0; j < 8; j++) aw[tid + j*256] = attn_W[tid + j*256];
    if (tid < C) ab[tid] = attn_b[tid];
    int ln = tid >> 5;
    if (active){
      xs[ln][h+0]=r[0]; xs[ln][h+1]=r[1]; xs[ln][h+2]=r[2]; xs[ln][h+3]=r[3];
    }
    __syncthreads();
    if (tid < 128){
      int n2 = tid >> 4, c = tid & 15;
      int node = blockIdx.x*8 + n2;
      if (node < N){
        float acc = ab[c];
        #pragma unroll 4
        for (int k = 0; k < H; k++)
          acc = fmaf(xs[n2][k], aw[k*C + c], acc);
        escore[(size_t)node*C + c] = __expf(acc);
      }
    }
  }
}

// partial[g][b][c][h] = strided-node partial of escore[n][c]*x[n][h]
__global__ __launch_bounds__(256) void k_clust(const u16* __restrict__ xb,
    const float* __restrict__ escore, const int* __restrict__ gs,
    float* __restrict__ partial){
  int g = blockIdx.x >> 4, b = blockIdx.x & 15;
  int h = threadIdx.x & 127, cg = threadIdx.x >> 7;
  int a = gs[g], e2 = gs[g+1];
  float acc[8] = {0,0,0,0,0,0,0,0};
  for (int n = a + b; n < e2; n += 16){
    float xv = bf2f(xb[(size_t)n*H + h]);
    const float4* ep = (const float4*)(escore + (size_t)n*C) + cg*2;
    float4 e0 = ep[0], e1 = ep[1];
    acc[0] = fmaf(e0.x, xv, acc[0]);
    acc[1] = fmaf(e0.y, xv, acc[1]);
    acc[2] = fmaf(e0.z, xv, acc[2]);
    acc[3] = fmaf(e0.w, xv, acc[3]);
    acc[4] = fmaf(e1.x, xv, acc[4]);
    acc[5] = fmaf(e1.y, xv, acc[5]);
    acc[6] = fmaf(e1.z, xv, acc[6]);
    acc[7] = fmaf(e1.w, xv, acc[7]);
  }
  int c0 = cg*8;
  float* dst = partial + (((size_t)(g*16 + b))*C)*H + h;
  #pragma unroll
  for (int r = 0; r < 8; r++)
    dst[(size_t)(c0 + r)*H] = acc[r];
}

// k_out with fused denom (sum of escore over the graph's nodes per cluster)
__global__ __launch_bounds__(256) void k_out(const float* __restrict__ partial,
    const float* __restrict__ escore, const int* __restrict__ gs,
    const float* __restrict__ out_W, const float* __restrict__ out_b,
    float* __restrict__ out){
  __shared__ float cs[2][128];
  __shared__ float dsum[4];
  int tid = threadIdx.x;
  int r = tid >> 7, h = tid & 127;
  int row = blockIdx.x*2 + r;          // (g,c) flat
  int g = row >> 4, c = row & 15;
  int a = gs[g], b2 = gs[g+1];
  // denom
  float s = 0.f;
  for (int n = a + h; n < b2; n += 128) s += escore[(size_t)n*C + c];
  s += __shfl_xor(s, 1, 64);  s += __shfl_xor(s, 2, 64);
  s += __shfl_xor(s, 4, 64);  s += __shfl_xor(s, 8, 64);
  s += __shfl_xor(s, 16, 64); s += __shfl_xor(s, 32, 64);
  if ((tid & 63) == 0) dsum[tid >> 6] = s;
  // cluster sum reduce
  float p = 0.f;
  for (int b = 0; b < 16; b++)
    p += partial[(((size_t)(g*16 + b))*C + c)*H + h];
  cs[r][h] = p;
  __syncthreads();
  float gden = dsum[r*2] + dsum[r*2 + 1];
  float inv = gden > 0.f ? 1.0f / gden : 0.f;
  float acc = 0.f;
  for (int hh = 0; hh < H; hh++)
    acc = fmaf(cs[r][hh], out_W[hh*ODIM + h], acc);
  out[(size_t)row*ODIM + h] = fmaf(acc, inv, out_b[h]);
}

// ---------------- host ----------------
extern "C" void kernel_launch(void* const* d_in, const int* in_sizes, int n_in,
                              void* d_out, int out_size, void* d_ws, size_t ws_size,
                              hipStream_t stream){
  const float* emb    = (const float*)d_in[0];
  const float* Wl     = (const float*)d_in[1];
  const float* bl     = (const float*)d_in[2];
  const float* Wr     = (const float*)d_in[3];
  const float* gamma  = (const float*)d_in[4];
  const float* beta   = (const float*)d_in[5];
  const float* attn_W = (const float*)d_in[6];
  const float* attn_b = (const float*)d_in[7];
  const float* out_W  = (const float*)d_in[8];
  const float* out_b  = (const float*)d_in[9];
  const int* deg    = (const int*)d_in[10];
  const int* ei     = (const int*)d_in[11];
  const int* batch  = (const int*)d_in[12];
  float* out = (float*)d_out;

  const int N = in_sizes[10];
  const int E = in_sizes[11] / 2;
  const int L = in_sizes[1] / (H*H);
  const int B = out_size / (C*ODIM);
  const int NB = (N + 127) >> 7;        // buckets of 128 nodes
  const int nbh = NB * NP;              // blkhist elements
  const int chunk = (E + NP - 1) / NP;  // edges per hist/place block
  const int nblkL = (N + 63) / 64;      // k_linear grid

  size_t off = 0;
  auto alloc = [&](size_t bytes) -> void* {
    void* p = (char*)d_ws + off;
    off += (bytes + 255) & ~(size_t)255;
    return p;
  };
  u16*   xb     = (u16*)  alloc((size_t)N*H*2);
  u32*   xq     = (u32*)  alloc((size_t)N*H);    // fp8 shadow of xb
  u16*   meanb  = (u16*)  alloc((size_t)N*H*2);
  u16*   x2b    = (u16*)  alloc((size_t)N*H*2);
  int2*  pairs  = (int2*) alloc((size_t)E*8);
  float* partial= (float*)alloc((size_t)B*16*C*H*4);  // dedicated (8.4 MB)
  u16*   Wt     = (u16*)  alloc((size_t)L*H*256*2);
  float* escore = (float*)alloc((size_t)N*C*4);
  int*   col    = (int*)  alloc((size_t)E*4);
  int*   rowptr = (int*)  alloc((size_t)(N+1)*4);
  int*   blkhist= (int*)  alloc((size_t)nbh*4);
  int*   bases  = (int*)  alloc((size_t)nbh*4);
  int*   bsum   = (int*)  alloc(256*4);
  int*   boff   = (int*)  alloc(256*4);
  int*   gs     = (int*)  alloc((size_t)(B+1)*4);
  float* stats  = (float*)alloc((size_t)L*2*H*4);
  float* pstats = (float*)alloc((size_t)nblkL*256*4);

  // fused setup
  int g0 = (N*32 + 255)/256;            // embed blocks
  int g1 = g0 + (N + 255)/256;          // + bounds
  int g2 = g1 + L*16;                   // + wprep
  int gT = g2 + NP;                     // + hist
  hipLaunchKernelGGL(k_setup, dim3(gT), dim3(256), 0, stream,
                     emb, deg, xb, xq, batch, gs, Wl, Wr, Wt, ei, blkhist,
                     N, B, NB, E, chunk, g0, g1, g2);
  int nblkS = (nbh + 1023) / 1024;
  hipLaunchKernelGGL(k_scanA, dim3(nblkS), dim3(256), 0, stream, blkhist, bases, bsum, nbh);
  hipLaunchKernelGGL(k_scanB, dim3(1),     dim3(256), 0, stream, bsum, boff, nblkS);
  hipLaunchKernelGGL(k_place, dim3(NP), dim3(256), 0, stream,
                     ei, bases, boff, pairs, NB, E, chunk);
  hipLaunchKernelGGL(k_cnt_place, dim3(NB), dim3(256), 0, stream,
                     pairs, bases, boff, rowptr, col, NB, N, E);

  float invN = 1.0f / (float)N;
  for (int l = 0; l < L; l++){
    hipLaunchKernelGGL(k_agg,    dim3((N+3)/4),  dim3(256), 0, stream, xq, rowptr, col, meanb, N);
    hipLaunchKernelGGL(k_linear, dim3(nblkL),    dim3(256), 0, stream,
                       meanb, xb, Wt + (size_t)l*H*256, bl + (size_t)l*H, x2b,
                       pstats, N);
    hipLaunchKernelGGL(k_statred,dim3(256),      dim3(256), 0, stream, pstats, stats + l*2*H, nblkL);
    hipLaunchKernelGGL(k_bnrelu, dim3((N*32+255)/256), dim3(256), 0, stream,
                       x2b, stats + l*2*H, gamma + (size_t)l*H, beta + (size_t)l*H,
                       xb, xq, N, invN, attn_W, attn_b, escore, (l == L-1) ? 1 : 0);
  }
  hipLaunchKernelGGL(k_clust, dim3(B*16),  dim3(256), 0, stream, xb, escore, gs, partial);
  hipLaunchKernelGGL(k_out,   dim3(B*C/2), dim3(256), 0, stream,
                     partial, escore, gs, out_W, out_b, out);
}

// Round 14
// 333.579 us; speedup vs baseline: 3.1378x; 1.0058x over previous
//
#include <hip/hip_runtime.h>

typedef unsigned short u16;
typedef unsigned int   u32;

#define H    128
#define C    16
#define ODIM 128

typedef short bf16x8 __attribute__((ext_vector_type(8)));
typedef float f32x4  __attribute__((ext_vector_type(4)));
typedef float f32x2v __attribute__((ext_vector_type(2)));

#define WSP 272   // Ws row stride (u16)
#define NP  256   // CSR partitions
#define NSH 16    // stat shards

__device__ __forceinline__ float bf2f(u32 v){
  union { u32 i; float f; } t; t.i = v << 16; return t.f;
}
__device__ __forceinline__ u16 f2bf(float f){
  u32 u = __float_as_uint(f);
  u32 r = u + 0x7fffu + ((u >> 16) & 1u);   // RNE
  return (u16)(r >> 16);
}
__device__ __forceinline__ u32 pack2(float a, float b){
  return (u32)f2bf(a) | ((u32)f2bf(b) << 16);
}
__device__ __forceinline__ u32 pack_fp8x4(float a, float b, float c, float d){
  int p = __builtin_amdgcn_cvt_pk_fp8_f32(a, b, 0, false);
  p     = __builtin_amdgcn_cvt_pk_fp8_f32(c, d, p, true);
  return (u32)p;
}

// ---------- fused setup: shard-zero | embed | bounds | wprep | hist ----------
__global__ __launch_bounds__(256) void k_setup(const float* __restrict__ emb,
    const int* __restrict__ deg, u16* __restrict__ xb, u32* __restrict__ xq,
    const int* __restrict__ batch, int* __restrict__ gs,
    const float* __restrict__ Wl, const float* __restrict__ Wr,
    u16* __restrict__ Wt, const int* __restrict__ ei,
    int* __restrict__ blkhist, float* __restrict__ statsh,
    int N, int B, int NB, int E, int chunk,
    int gz, int g0, int g1, int g2){
  __shared__ __align__(16) char smem[4608];
  int bid = blockIdx.x, tid = threadIdx.x;
  if (bid < gz){
    // ---- zero stat shards ----
    statsh[bid*256 + tid] = 0.f;
  } else if (bid < g0){
    // ---- embed ----
    int i = (bid - gz)*256 + tid;
    if (i < N*32){
      int n = i >> 5, q = i & 31;
      int d = deg[n];
      float4 v = ((const float4*)(emb + (size_t)d*H))[q];
      uint2 o; o.x = pack2(v.x, v.y); o.y = pack2(v.z, v.w);
      ((uint2*)(xb + (size_t)n*H))[q] = o;
      xq[i] = pack_fp8x4(v.x, v.y, v.z, v.w);
    }
  } else if (bid < g1){
    // ---- bounds ----
    int n = (bid - g0)*256 + tid;
    if (n < N){
      int b = batch[n];
      if (n == 0){ for (int g = 0; g <= b; g++) gs[g] = 0; }
      else {
        int pb = batch[n-1];
        for (int g = pb+1; g <= b; g++) gs[g] = n;
      }
      if (n == N-1){ for (int g = b+1; g <= B; g++) gs[g] = N; }
    }
  } else if (bid < g2){
    // ---- wprep: Wt[l][h][k] ----
    u16 (*T)[18] = (u16(*)[18])smem;
    int b = bid - g1;
    int strip = b & 7, half = (b >> 3) & 1, l = b >> 4;
    const float* M = (half ? Wr : Wl) + (size_t)l*H*H;
    int k0 = strip * 16;
    #pragma unroll
    for (int j = 0; j < 8; j++){
      int u = tid + j*256;
      int kk = u >> 7, h = u & 127;
      T[h][kk] = f2bf(M[(size_t)(k0 + kk)*H + h]);
    }
    __syncthreads();
    #pragma unroll
    for (int j = 0; j < 8; j++){
      int u = tid + j*256;
      int h = u >> 4, k16 = u & 15;
      Wt[((size_t)(l*H + h))*256 + half*128 + k0 + k16] = T[h][k16];
    }
  } else {
    // ---- hist ----
    int* hist = (int*)smem;
    int blk = bid - g2;
    for (int b = tid; b < NB; b += 256) hist[b] = 0;
    __syncthreads();
    int start = blk*chunk, end = min(E, start + chunk);
    for (int e = start + tid; e < end; e += 256)
      atomicAdd(&hist[ei[E + e] >> 7], 1);
    __syncthreads();
    for (int b = tid; b < NB; b += 256) blkhist[b*NP + blk] = hist[b];
  }
}

// generic scan over n ints (1024 per block); writes per-block totals to bsum
__global__ __launch_bounds__(256) void k_scanA(const int* __restrict__ in,
    int* __restrict__ out, int* __restrict__ bsum, int n){
  __shared__ int wsum[4];
  int tid = threadIdx.x;
  int base = blockIdx.x*1024 + tid*4;
  int v0 = (base+0 < n) ? in[base+0] : 0;
  int v1 = (base+1 < n) ? in[base+1] : 0;
  int v2 = (base+2 < n) ? in[base+2] : 0;
  int v3 = (base+3 < n) ? in[base+3] : 0;
  int tsum = v0+v1+v2+v3;
  int lane = tid & 63, w = tid >> 6;
  int incl = tsum;
  for (int d = 1; d < 64; d <<= 1){
    int t = __shfl_up(incl, d, 64);
    if (lane >= d) incl += t;
  }
  if (lane == 63) wsum[w] = incl;
  __syncthreads();
  int woff = 0;
  for (int i = 0; i < w; i++) woff += wsum[i];
  int excl = woff + incl - tsum;
  if (base+0 < n) out[base+0] = excl;
  if (base+1 < n) out[base+1] = excl + v0;
  if (base+2 < n) out[base+2] = excl + v0 + v1;
  if (base+3 < n) out[base+3] = excl + v0 + v1 + v2;
  if (tid == 255) bsum[blockIdx.x] = woff + incl;
}

// in-block exclusive scan of bsum[0..nb) -> bo[0..255] (nb <= 256)
__device__ __forceinline__ void scan_bsum(const int* __restrict__ bsum,
    int* bo, int nb, int tid){
  __shared__ int ws2[4];
  int v = (tid < nb) ? bsum[tid] : 0;
  int lane = tid & 63, w = tid >> 6;
  int incl = v;
  for (int d = 1; d < 64; d <<= 1){
    int t = __shfl_up(incl, d, 64);
    if (lane >= d) incl += t;
  }
  if (lane == 63) ws2[w] = incl;
  __syncthreads();
  int woff = 0;
  for (int i = 0; i < w; i++) woff += ws2[i];
  bo[tid] = woff + incl - v;
  __syncthreads();
}

// place edges bucket-sorted as (src,dst) pairs; boff computed locally
__global__ __launch_bounds__(256) void k_place(const int* __restrict__ ei,
    const int* __restrict__ bases, const int* __restrict__ bsum,
    int2* __restrict__ pairs, int NB, int E, int chunk, int nbs){
  __shared__ int cursor[400];
  __shared__ int bo[256];
  int blk = blockIdx.x, tid = threadIdx.x;
  scan_bsum(bsum, bo, nbs, tid);
  for (int b = tid; b < NB; b += 256){
    int i = b*NP + blk;
    cursor[b] = bases[i] + bo[i >> 10];
  }
  __syncthreads();
  int start = blk*chunk, end = min(E, start + chunk);
  for (int e = start + tid; e < end; e += 256){
    int s = ei[e], d = ei[E + e];
    int pos = atomicAdd(&cursor[d >> 7], 1);
    pairs[pos] = make_int2(s, d);
  }
}

// per bucket: per-node counts -> rowptr (direct), then node-sort col
__global__ __launch_bounds__(256) void k_cnt_place(const int2* __restrict__ pairs,
    const int* __restrict__ bases, const int* __restrict__ bsum,
    int* __restrict__ rowptr, int* __restrict__ col,
    int NB, int N, int E, int nbs){
  int b = blockIdx.x, tid = threadIdx.x;
  __shared__ int bo[256];
  scan_bsum(bsum, bo, nbs, tid);
  int i0 = b*NP;
  int bstart = bases[i0] + bo[i0 >> 10];
  int bend = E;
  if (b+1 < NB){ int i1 = (b+1)*NP; bend = bases[i1] + bo[i1 >> 10]; }
  __shared__ int cnt[128], sc[128], rank[128];
  if (tid < 128) cnt[tid] = 0;
  __syncthreads();
  for (int e = bstart + tid; e < bend; e += 256)
    atomicAdd(&cnt[pairs[e].y & 127], 1);
  __syncthreads();
  if (tid < 128) sc[tid] = cnt[tid];
  for (int d = 1; d < 128; d <<= 1){
    int v = 0;
    __syncthreads();
    if (tid < 128 && tid >= d) v = sc[tid - d];
    __syncthreads();
    if (tid < 128) sc[tid] += v;
  }
  __syncthreads();
  if (tid < 128){
    int excl = sc[tid] - cnt[tid];
    rank[tid] = bstart + excl;
    int node = b*128 + tid;
    if (node < N) rowptr[node] = bstart + excl;
  }
  if (b == NB-1 && tid == 0) rowptr[N] = E;
  __syncthreads();
  for (int e = bstart + tid; e < bend; e += 256){
    int2 p = pairs[e];
    int pos = atomicAdd(&rank[p.y & 127], 1);
    col[pos] = p.x;
  }
}

// ---------------- per-layer ----------------
// wave per node; fp8 row = 128 B = 8 lanes x uint4, 8 edges/VMEM-instr,
// packed f32 accumulate (v_pk_add_f32).
__device__ __forceinline__ void dec16v(f32x2v* a, uint4 v){
  a[0] += __builtin_amdgcn_cvt_pk_f32_fp8((int)v.x, false);
  a[1] += __builtin_amdgcn_cvt_pk_f32_fp8((int)v.x, true );
  a[2] += __builtin_amdgcn_cvt_pk_f32_fp8((int)v.y, false);
  a[3] += __builtin_amdgcn_cvt_pk_f32_fp8((int)v.y, true );
  a[4] += __builtin_amdgcn_cvt_pk_f32_fp8((int)v.z, false);
  a[5] += __builtin_amdgcn_cvt_pk_f32_fp8((int)v.z, true );
  a[6] += __builtin_amdgcn_cvt_pk_f32_fp8((int)v.w, false);
  a[7] += __builtin_amdgcn_cvt_pk_f32_fp8((int)v.w, true );
}

__global__ __launch_bounds__(256) void k_agg(const u32* __restrict__ xq,
    const int* __restrict__ rowptr, const int* __restrict__ col,
    u16* __restrict__ meanb, int N){
  int wid  = (blockIdx.x*256 + threadIdx.x) >> 6;
  int lane = threadIdx.x & 63;
  if (wid >= N) return;
  int r0 = rowptr[wid], r1 = rowptr[wid+1];
  int grp = lane >> 3, fl = lane & 7;   // 8 groups x 8 lanes
  const u32* xf = xq + fl*4;            // 16 fp8 features per lane
  f32x2v a[8];
  #pragma unroll
  for (int j = 0; j < 8; j++) a[j] = (f32x2v){0.f, 0.f};
  int e = r0 + grp;
  for (; e + 8 < r1; e += 16){
    uint4 v = *(const uint4*)(xf + (size_t)col[e]*32);
    uint4 u = *(const uint4*)(xf + (size_t)col[e+8]*32);
    dec16v(a, v);
    dec16v(a, u);
  }
  if (e < r1){
    uint4 v = *(const uint4*)(xf + (size_t)col[e]*32);
    dec16v(a, v);
  }
  #pragma unroll
  for (int j = 0; j < 8; j++){
    a[j].x += __shfl_xor(a[j].x, 8, 64);  a[j].y += __shfl_xor(a[j].y, 8, 64);
    a[j].x += __shfl_xor(a[j].x, 16, 64); a[j].y += __shfl_xor(a[j].y, 16, 64);
    a[j].x += __shfl_xor(a[j].x, 32, 64); a[j].y += __shfl_xor(a[j].y, 32, 64);
  }
  if (grp == 0){
    float invc = 1.0f / (float)max(r1 - r0, 1);
    uint4 o0, o1;
    o0.x = pack2(a[0].x*invc, a[0].y*invc);
    o0.y = pack2(a[1].x*invc, a[1].y*invc);
    o0.z = pack2(a[2].x*invc, a[2].y*invc);
    o0.w = pack2(a[3].x*invc, a[3].y*invc);
    o1.x = pack2(a[4].x*invc, a[4].y*invc);
    o1.y = pack2(a[5].x*invc, a[5].y*invc);
    o1.z = pack2(a[6].x*invc, a[6].y*invc);
    o1.w = pack2(a[7].x*invc, a[7].y*invc);
    u16* mp = meanb + (size_t)wid*H + fl*16;
    *(uint4*)mp       = o0;
    *(uint4*)(mp + 8) = o1;
  }
}

// x2b[n][h] (bf16) = bl[h] + [meanb|xb] @ Wt^T via mfma_f32_16x16x32_bf16.
// Wt staged whole in LDS; A-fragments direct from global. BN-stat block sums
// -> 16 global atomic shards (49-deep chains; NO fences).
__global__ __launch_bounds__(256) void k_linear(const u16* __restrict__ meanb,
    const u16* __restrict__ xb, const u16* __restrict__ Wt,
    const float* __restrict__ bl, u16* __restrict__ x2b,
    float* __restrict__ statsh_l, int N){
  __shared__ u16 Ws[128][WSP];         // 69.6 KB -> 2 blocks/CU
  __shared__ float Sh[128], Qh[128];
  int tid = threadIdx.x;
  if (tid < 128){ Sh[tid] = 0.f; Qh[tid] = 0.f; }
  int lane = tid & 63, w = tid >> 6;
  int mlane = lane & 15, quad = lane >> 4;
  int node = blockIdx.x*64 + w*16 + mlane;
  const u16* arow_m = meanb + (size_t)node*H + quad*8;
  const u16* arow_x = xb   + (size_t)node*H + quad*8;
  bf16x8 af[8];
  #pragma unroll
  for (int kk = 0; kk < 4; kk++){
    af[kk]     = *(const bf16x8*)(arow_m + kk*32);
    af[kk + 4] = *(const bf16x8*)(arow_x + kk*32);
  }
  #pragma unroll
  for (int j = 0; j < 16; j++){
    int u = tid + j*256;
    int row = u >> 5, seg = u & 31;
    uint4 v = ((const uint4*)(Wt + (size_t)row*256))[seg];
    *(uint4*)&Ws[row][seg*8] = v;
  }
  __syncthreads();
  f32x4 acc[8];
  #pragma unroll
  for (int t = 0; t < 8; t++) acc[t] = (f32x4){0.f, 0.f, 0.f, 0.f};
  #pragma unroll
  for (int kk = 0; kk < 8; kk++){
    #pragma unroll
    for (int t = 0; t < 8; t++){
      bf16x8 b = *(const bf16x8*)&Ws[t*16 + mlane][kk*32 + quad*8];
      acc[t] = __builtin_amdgcn_mfma_f32_16x16x32_bf16(af[kk], b, acc[t], 0, 0, 0);
    }
  }
  #pragma unroll
  for (int t = 0; t < 8; t++){
    int h = t*16 + mlane;
    float bv = bl[h];
    float s = 0.f, q = 0.f;
    #pragma unroll
    for (int r = 0; r < 4; r++){
      int nd = blockIdx.x*64 + w*16 + quad*4 + r;
      if (nd < N){
        float v = acc[t][r] + bv;
        x2b[(size_t)nd*H + h] = f2bf(v);
        s += v; q = fmaf(v, v, q);
      }
    }
    s += __shfl_xor(s, 16, 64); s += __shfl_xor(s, 32, 64);
    q += __shfl_xor(q, 16, 64); q += __shfl_xor(q, 32, 64);
    if (quad == 0){
      atomicAdd(&Sh[h], s);
      atomicAdd(&Qh[h], q);
    }
  }
  __syncthreads();
  {
    float v = (tid < 128) ? Sh[tid] : Qh[tid - 128];
    atomicAdd(&statsh_l[(blockIdx.x & (NSH-1))*256 + tid], v);
  }
}

// BN+ReLU (reads bf16 x2b); sums 16 stat shards into LDS at start;
// writes xb + xq; do_scores fuses attention scores.
__global__ __launch_bounds__(256) void k_bnrelu(const u16* __restrict__ x2b,
    const float* __restrict__ statsh_l, const float* __restrict__ gamma,
    const float* __restrict__ beta, u16* __restrict__ xb, u32* __restrict__ xq,
    int N, float invN,
    const float* __restrict__ attn_W, const float* __restrict__ attn_b,
    float* __restrict__ escore, int do_scores){
  __shared__ float st[256];
  __shared__ float xs[8][132];
  __shared__ float aw[H*C];
  __shared__ float ab[C];
  int tid = threadIdx.x;
  {
    float sacc = 0.f;
    #pragma unroll
    for (int s2 = 0; s2 < NSH; s2++) sacc += statsh_l[s2*256 + tid];
    st[tid] = sacc;
  }
  __syncthreads();
  int i = blockIdx.x*256 + tid;
  bool active = (i < N*32);
  int h = (tid & 31) * 4;
  float r[4] = {0.f, 0.f, 0.f, 0.f};
  if (active){
    uint2 o2 = ((const uint2*)x2b)[i];
    float vv[4] = {bf2f(o2.x & 0xffff), bf2f(o2.x >> 16),
                   bf2f(o2.y & 0xffff), bf2f(o2.y >> 16)};
    #pragma unroll
    for (int j = 0; j < 4; j++){
      float mu  = st[h+j] * invN;
      float var = fmaf(-mu, mu, st[H + h + j] * invN);
      float sc  = rsqrtf(var + 1e-5f) * gamma[h+j];
      float bi  = beta[h+j];
      r[j] = fmaxf(fmaf(vv[j] - mu, sc, bi), 0.0f);
    }
    uint2 o; o.x = pack2(r[0], r[1]); o.y = pack2(r[2], r[3]);
    ((uint2*)xb)[i] = o;
    xq[i] = pack_fp8x4(r[0], r[1], r[2], r[3]);
  }
  if (do_scores){
    #pragma unroll
    for (int j = 0; j < 8; j++) aw[tid + j*256] = attn_W[tid + j*256];
    if (tid < C) ab[tid] = attn_b[tid];
    int ln = tid >> 5;
    if (active){
      xs[ln][h+0]=r[0]; xs[ln][h+1]=r[1]; xs[ln][h+2]=r[2]; xs[ln][h+3]=r[3];
    }
    __syncthreads();
    if (tid < 128){
      int n2 = tid >> 4, c = tid & 15;
      int node = blockIdx.x*8 + n2;
      if (node < N){
        float acc = ab[c];
        #pragma unroll 4
        for (int k = 0; k < H; k++)
          acc = fmaf(xs[n2][k], aw[k*C + c], acc);
        escore[(size_t)node*C + c] = __expf(acc);
      }
    }
  }
}

// partial[g][b][c][h] = strided-node partial of escore[n][c]*x[n][h]
__global__ __launch_bounds__(256) void k_clust(const u16* __restrict__ xb,
    const float* __restrict__ escore, const int* __restrict__ gs,
    float* __restrict__ partial){
  int g = blockIdx.x >> 4, b = blockIdx.x & 15;
  int h = threadIdx.x & 127, cg = threadIdx.x >> 7;
  int a = gs[g], e2 = gs[g+1];
  float acc[8] = {0,0,0,0,0,0,0,0};
  for (int n = a + b; n < e2; n += 16){
    float xv = bf2f(xb[(size_t)n*H + h]);
    const float4* ep = (const float4*)(escore + (size_t)n*C) + cg*2;
    float4 e0 = ep[0], e1 = ep[1];
    acc[0] = fmaf(e0.x, xv, acc[0]);
    acc[1] = fmaf(e0.y, xv, acc[1]);
    acc[2] = fmaf(e0.z, xv, acc[2]);
    acc[3] = fmaf(e0.w, xv, acc[3]);
    acc[4] = fmaf(e1.x, xv, acc[4]);
    acc[5] = fmaf(e1.y, xv, acc[5]);
    acc[6] = fmaf(e1.z, xv, acc[6]);
    acc[7] = fmaf(e1.w, xv, acc[7]);
  }
  int c0 = cg*8;
  float* dst = partial + (((size_t)(g*16 + b))*C)*H + h;
  #pragma unroll
  for (int r = 0; r < 8; r++)
    dst[(size_t)(c0 + r)*H] = acc[r];
}

// k_out with fused denom (sum of escore over the graph's nodes per cluster)
__global__ __launch_bounds__(256) void k_out(const float* __restrict__ partial,
    const float* __restrict__ escore, const int* __restrict__ gs,
    const float* __restrict__ out_W, const float* __restrict__ out_b,
    float* __restrict__ out){
  __shared__ float cs[2][128];
  __shared__ float dsum[4];
  int tid = threadIdx.x;
  int r = tid >> 7, h = tid & 127;
  int row = blockIdx.x*2 + r;          // (g,c) flat
  int g = row >> 4, c = row & 15;
  int a = gs[g], b2 = gs[g+1];
  // denom
  float s = 0.f;
  for (int n = a + h; n < b2; n += 128) s += escore[(size_t)n*C + c];
  s += __shfl_xor(s, 1, 64);  s += __shfl_xor(s, 2, 64);
  s += __shfl_xor(s, 4, 64);  s += __shfl_xor(s, 8, 64);
  s += __shfl_xor(s, 16, 64); s += __shfl_xor(s, 32, 64);
  if ((tid & 63) == 0) dsum[tid >> 6] = s;
  // cluster sum reduce
  float p = 0.f;
  for (int b = 0; b < 16; b++)
    p += partial[(((size_t)(g*16 + b))*C + c)*H + h];
  cs[r][h] = p;
  __syncthreads();
  float gden = dsum[r*2] + dsum[r*2 + 1];
  float inv = gden > 0.f ? 1.0f / gden : 0.f;
  float acc = 0.f;
  for (int hh = 0; hh < H; hh++)
    acc = fmaf(cs[r][hh], out_W[hh*ODIM + h], acc);
  out[(size_t)row*ODIM + h] = fmaf(acc, inv, out_b[h]);
}

// ---------------- host ----------------
extern "C" void kernel_launch(void* const* d_in, const int* in_sizes, int n_in,
                              void* d_out, int out_size, void* d_ws, size_t ws_size,
                              hipStream_t stream){
  const float* emb    = (const float*)d_in[0];
  const float* Wl     = (const float*)d_in[1];
  const float* bl     = (const float*)d_in[2];
  const float* Wr     = (const float*)d_in[3];
  const float* gamma  = (const float*)d_in[4];
  const float* beta   = (const float*)d_in[5];
  const float* attn_W = (const float*)d_in[6];
  const float* attn_b = (const float*)d_in[7];
  const float* out_W  = (const float*)d_in[8];
  const float* out_b  = (const float*)d_in[9];
  const int* deg    = (const int*)d_in[10];
  const int* ei     = (const int*)d_in[11];
  const int* batch  = (const int*)d_in[12];
  float* out = (float*)d_out;

  const int N = in_sizes[10];
  const int E = in_sizes[11] / 2;
  const int L = in_sizes[1] / (H*H);
  const int B = out_size / (C*ODIM);
  const int NB = (N + 127) >> 7;        // buckets of 128 nodes
  const int nbh = NB * NP;              // blkhist elements
  const int chunk = (E + NP - 1) / NP;  // edges per hist/place block
  const int nblkL = (N + 63) / 64;      // k_linear grid

  size_t off = 0;
  auto alloc = [&](size_t bytes) -> void* {
    void* p = (char*)d_ws + off;
    off += (bytes + 255) & ~(size_t)255;
    return p;
  };
  u16*   xb     = (u16*)  alloc((size_t)N*H*2);
  u32*   xq     = (u32*)  alloc((size_t)N*H);    // fp8 shadow of xb
  u16*   meanb  = (u16*)  alloc((size_t)N*H*2);
  u16*   x2b    = (u16*)  alloc((size_t)N*H*2);
  int2*  pairs  = (int2*) alloc((size_t)E*8);
  float* partial= (float*)alloc((size_t)B*16*C*H*4);  // dedicated (8.4 MB)
  u16*   Wt     = (u16*)  alloc((size_t)L*H*256*2);
  float* escore = (float*)alloc((size_t)N*C*4);
  int*   col    = (int*)  alloc((size_t)E*4);
  int*   rowptr = (int*)  alloc((size_t)(N+1)*4);
  int*   blkhist= (int*)  alloc((size_t)nbh*4);
  int*   bases  = (int*)  alloc((size_t)nbh*4);
  int*   bsum   = (int*)  alloc(256*4);
  int*   gs     = (int*)  alloc((size_t)(B+1)*4);
  float* statsh = (float*)alloc((size_t)L*NSH*256*4);  // stat shards

  // fused setup
  int gz = L*NSH;                       // shard-zero blocks (NSH*256 floats each L)
  int g0 = gz + (N*32 + 255)/256;       // + embed
  int g1 = g0 + (N + 255)/256;          // + bounds
  int g2 = g1 + L*16;                   // + wprep
  int gT = g2 + NP;                     // + hist
  hipLaunchKernelGGL(k_setup, dim3(gT), dim3(256), 0, stream,
                     emb, deg, xb, xq, batch, gs, Wl, Wr, Wt, ei, blkhist,
                     statsh, N, B, NB, E, chunk, gz, g0, g1, g2);
  int nblkS = (nbh + 1023) / 1024;
  hipLaunchKernelGGL(k_scanA, dim3(nblkS), dim3(256), 0, stream, blkhist, bases, bsum, nbh);
  hipLaunchKernelGGL(k_place, dim3(NP), dim3(256), 0, stream,
                     ei, bases, bsum, pairs, NB, E, chunk, nblkS);
  hipLaunchKernelGGL(k_cnt_place, dim3(NB), dim3(256), 0, stream,
                     pairs, bases, bsum, rowptr, col, NB, N, E, nblkS);

  float invN = 1.0f / (float)N;
  for (int l = 0; l < L; l++){
    float* sh_l = statsh + (size_t)l*NSH*256;
    hipLaunchKernelGGL(k_agg,    dim3((N+3)/4),  dim3(256), 0, stream, xq, rowptr, col, meanb, N);
    hipLaunchKernelGGL(k_linear, dim3(nblkL),    dim3(256), 0, stream,
                       meanb, xb, Wt + (size_t)l*H*256, bl + (size_t)l*H, x2b,
                       sh_l, N);
    hipLaunchKernelGGL(k_bnrelu, dim3((N*32+255)/256), dim3(256), 0, stream,
                       x2b, sh_l, gamma + (size_t)l*H, beta + (size_t)l*H,
                       xb, xq, N, invN, attn_W, attn_b, escore, (l == L-1) ? 1 : 0);
  }
  hipLaunchKernelGGL(k_clust, dim3(B*16),  dim3(256), 0, stream, xb, escore, gs, partial);
  hipLaunchKernelGGL(k_out,   dim3(B*C/2), dim3(256), 0, stream,
                     partial, escore, gs, out_W, out_b, out);
}